// Round 4
// baseline (427.833 us; speedup 1.0000x reference)
//
#include <hip/hip_runtime.h>
#include <hip/hip_cooperative_groups.h>
#include <math.h>

namespace cg = cooperative_groups;

#define EPSF 1e-5f

// B=256, C=3, H=W=64 (HW=4096), G=128
// ws layout (float offsets)
constexpr int OFF_RED1 = 0;        // 256*6  bn1 partials per-b (sum0..2, sq0..2)
constexpr int OFF_RED2 = 2048;     // 256*9  t-moment partials
constexpr int OFF_W2E  = 8192;     // 128*128*9 effective conv2 weights
constexpr int OFF_M    = OFF_W2E + 128 * 128 * 9;  // 256*128 pooled conv2 output

__device__ __forceinline__ float wave_sum(float v) {
    #pragma unroll
    for (int off = 32; off > 0; off >>= 1) v += __shfl_down(v, off);
    return v;
}

struct Prm {
    const float *world, *agent, *action;
    const float *bn1_g, *bn1_b, *conv1w, *bn2_g, *bn2_b, *conv2w, *bn3_g, *bn3_b;
    const float *fc1w, *fc1b, *lnmig, *lnmib, *miw1, *miw2;
    const float *embc, *embe, *embnc, *embns, *embp;
    const float *lncag, *lncab, *caw1, *cab1, *caw2, *cab2, *lncg, *lncb, *cw;
    const float *lndg, *lndb, *dw1, *dw2;
    float *red1, *red2, *w2e, *m, *out;
};

// One cooperative kernel: 256 blocks (one per batch image) x 512 threads.
// Phases separated by grid.sync(); LDS t-planes persist across syncs.
__global__ __launch_bounds__(512) void kAll(Prm p) {
    cg::grid_group grid = cg::this_grid();
    __shared__ __align__(16) float lds[12288];   // x then t planes [c][4096]; reused for reductions
    __shared__ __align__(16) float Fsh[1152];
    __shared__ float wt[384], bt[128], momp[288], mom[9], ab[6];
    __shared__ float rw[8][10];                  // per-wave reduction scratch
    __shared__ float pp[96];
    // head scratch
    __shared__ float r8[8][128], xsh[128];
    __shared__ float lnv[28], lnca[24], lnsc[56], h1[100], h2[100], h3[50], cat[60];

    int b = blockIdx.x, tid = threadIdx.x;
    int wv = tid >> 6, ln = tid & 63;

    // ================= phase 1: stage raw x + bn1 partials + w2e =================
    {
        const float4* xb = (const float4*)(p.world + (size_t)b * 12288);
        float s0 = 0, s1 = 0, s2 = 0, q0 = 0, q1 = 0, q2 = 0;
        #pragma unroll
        for (int k = 0; k < 6; ++k) {
            int i = k * 512 + tid;
            float4 v = xb[i];
            *(float4*)&lds[i << 2] = v;
            float t = (v.x + v.y) + (v.z + v.w);
            float t2 = fmaf(v.x, v.x, fmaf(v.y, v.y, fmaf(v.z, v.z, v.w * v.w)));
            if (k < 2)      { s0 += t; q0 += t2; }
            else if (k < 4) { s1 += t; q1 += t2; }
            else            { s2 += t; q2 += t2; }
        }
        float r0 = wave_sum(s0), r1 = wave_sum(s1), r2 = wave_sum(s2);
        float r3 = wave_sum(q0), r4 = wave_sum(q1), r5 = wave_sum(q2);
        if (ln == 0) {
            rw[wv][0] = r0; rw[wv][1] = r1; rw[wv][2] = r2;
            rw[wv][3] = r3; rw[wv][4] = r4; rw[wv][5] = r5;
        }
        __syncthreads();
        if (tid < 6) {
            float s = 0;
            #pragma unroll
            for (int w = 0; w < 8; ++w) s += rw[w][tid];
            p.red1[b * 6 + tid] = s;
        }
        if (tid < 64) {  // 64 (g,g') pairs per block
            int idx = b * 64 + tid;
            int g = idx >> 7, gp = idx & 127;
            const float* wp = p.conv2w + (size_t)(g * 128 + gp) * 9;  // [ky][kx]
            float v0 = wp[0], v1 = wp[1], v2 = wp[2], v3 = wp[3], v4 = wp[4],
                  v5 = wp[5], v6 = wp[6], v7 = wp[7], v8 = wp[8];
            float c[9];
            c[0] = ((v0 + v1) + (v2 + v3)) + ((v4 + v5) + (v6 + v7)) + v8;
            c[1] = -(v6 + v7 + v8);
            c[2] = -(v0 + v1 + v2);
            c[3] = -(v2 + v5 + v8);
            c[4] = -(v0 + v3 + v6);
            c[5] = v8; c[6] = v6; c[7] = v2; c[8] = v0;
            #pragma unroll
            for (int k = 0; k < 9; ++k) {
                int jj = gp * 9 + k;                                       // 0..1151
                p.w2e[(size_t)(jj >> 2) * 512 + g * 4 + (jj & 3)] = c[k];  // [jblk][g][4]
            }
        }
    }
    __threadfence();
    grid.sync();

    // ================= phase 2: bn1 finalize + x->t + moments =================
    if (tid < 96) {  // k = tid%6, 16 segs of 16 b
        int k = tid % 6, seg = tid / 6;
        float s = 0;
        #pragma unroll
        for (int i = 0; i < 16; ++i) s += p.red1[(seg * 16 + i) * 6 + k];
        pp[seg * 6 + k] = s;
    }
    __syncthreads();
    if (tid < 3) {
        float s = 0, s2 = 0;
        #pragma unroll
        for (int seg = 0; seg < 16; ++seg) { s += pp[seg * 6 + tid]; s2 += pp[seg * 6 + 3 + tid]; }
        float n = 256.f * 4096.f;
        float mean = s / n, var = s2 / n - mean * mean;
        float a = p.bn1_g[tid] * rsqrtf(var + EPSF);
        ab[tid] = a; ab[3 + tid] = p.bn1_b[tid] - mean * a;
    }
    __syncthreads();
    {
        float A0 = ab[0], A1 = ab[1], A2 = ab[2];
        float B0 = ab[3], B1 = ab[4], B2 = ab[5];
        #pragma unroll
        for (int k = 0; k < 6; ++k) {
            int i = k * 512 + tid;
            float4 v = *(float4*)&lds[i << 2];
            float a = (k < 2) ? A0 : ((k < 4) ? A1 : A2);
            float bb = (k < 2) ? B0 : ((k < 4) ? B1 : B2);
            v.x = fmaxf(0.f, fmaf(a, v.x, bb));
            v.y = fmaxf(0.f, fmaf(a, v.y, bb));
            v.z = fmaxf(0.f, fmaf(a, v.z, bb));
            v.w = fmaxf(0.f, fmaf(a, v.w, bb));
            *(float4*)&lds[i << 2] = v;
        }
    }
    __syncthreads();
    {
        float acc[9] = {0, 0, 0, 0, 0, 0, 0, 0, 0};
        for (int ii = tid; ii < 4096; ii += 512) {
            float t0 = lds[ii], t1 = lds[4096 + ii], t2 = lds[8192 + ii];
            acc[0] += t0; acc[1] += t1; acc[2] += t2;
            acc[3] = fmaf(t0, t0, acc[3]); acc[4] = fmaf(t0, t1, acc[4]);
            acc[5] = fmaf(t0, t2, acc[5]); acc[6] = fmaf(t1, t1, acc[6]);
            acc[7] = fmaf(t1, t2, acc[7]); acc[8] = fmaf(t2, t2, acc[8]);
        }
        #pragma unroll
        for (int k = 0; k < 9; ++k) {
            float v = wave_sum(acc[k]);
            if (ln == 0) rw[wv][k] = v;
        }
        __syncthreads();
        if (tid < 9) {
            float s = 0;
            #pragma unroll
            for (int w = 0; w < 8; ++w) s += rw[w][tid];
            p.red2[b * 9 + tid] = s;
        }
    }
    __threadfence();
    grid.sync();

    // ================= phase 3: bn2 fold + features + contract -> m =================
    if (tid < 288) {  // 32 segs x 9 moments, 8 rows each
        int seg = tid / 9, k = tid - seg * 9;
        float s = 0.f;
        #pragma unroll
        for (int r = 0; r < 8; ++r) s += p.red2[(seg * 8 + r) * 9 + k];
        momp[tid] = s;
    }
    __syncthreads();
    if (tid < 9) {
        float s = 0.f;
        #pragma unroll
        for (int sg = 0; sg < 32; ++sg) s += momp[sg * 9 + tid];
        mom[tid] = s / (256.f * 4096.f);
    }
    __syncthreads();
    if (tid < 128) {  // bn2 fold into conv1 weights
        int g = tid;
        float wa = p.conv1w[g * 3 + 0], wb = p.conv1w[g * 3 + 1], wc = p.conv1w[g * 3 + 2];
        float mean = wa * mom[0] + wb * mom[1] + wc * mom[2];
        float ey2 = wa * wa * mom[3] + wb * wb * mom[6] + wc * wc * mom[8]
                  + 2.f * (wa * wb * mom[4] + wa * wc * mom[5] + wb * wc * mom[7]);
        float var = ey2 - mean * mean;
        float a = p.bn2_g[g] * rsqrtf(var + EPSF);
        wt[g * 3 + 0] = a * wa; wt[g * 3 + 1] = a * wb; wt[g * 3 + 2] = a * wc;
        bt[g] = p.bn2_b[g] - mean * a;
    }
    __syncthreads();
    {
        int gl = tid & 31, q = tid >> 5;  // 16 chunks x 256 pixels; 4 g's per thread
        float w0[4], w1v[4], w2v[4], bw[4], S[4] = {0, 0, 0, 0};
        #pragma unroll
        for (int j = 0; j < 4; ++j) {
            int g = gl + 32 * j;
            w0[j] = wt[g * 3 + 0]; w1v[j] = wt[g * 3 + 1];
            w2v[j] = wt[g * 3 + 2]; bw[j] = bt[g];
        }
        int base = q * 256;
        #pragma unroll 4
        for (int i = 0; i < 64; ++i) {
            int ppx = base + i * 4;
            float4 t0 = *(const float4*)&lds[ppx];
            float4 t1 = *(const float4*)&lds[4096 + ppx];
            float4 t2 = *(const float4*)&lds[8192 + ppx];
            #pragma unroll
            for (int j = 0; j < 4; ++j) {
                float u0 = fmaxf(0.f, fmaf(w0[j], t0.x, fmaf(w1v[j], t1.x, fmaf(w2v[j], t2.x, bw[j]))));
                float u1 = fmaxf(0.f, fmaf(w0[j], t0.y, fmaf(w1v[j], t1.y, fmaf(w2v[j], t2.y, bw[j]))));
                float u2 = fmaxf(0.f, fmaf(w0[j], t0.z, fmaf(w1v[j], t1.z, fmaf(w2v[j], t2.z, bw[j]))));
                float u3 = fmaxf(0.f, fmaf(w0[j], t0.w, fmaf(w1v[j], t1.w, fmaf(w2v[j], t2.w, bw[j]))));
                S[j] += (u0 + u1) + (u2 + u3);
            }
        }
        // boundary post-pass: 128 g x 4 tasks, one thread each (reads t planes)
        {
            int g = tid & 127, task = tid >> 7;
            float vw0 = wt[g * 3 + 0], vw1 = wt[g * 3 + 1], vw2 = wt[g * 3 + 2], vb = bt[g];
            float s = 0.f, first = 0.f, last = 0.f;
            int p0 = (task == 1) ? 63 * 64 : ((task == 3) ? 63 : 0);
            int stp = (task >= 2) ? 64 : 1;
            #pragma unroll 4
            for (int i = 0; i < 64; ++i) {
                int px = p0 + i * stp;
                float u = fmaxf(0.f, fmaf(vw0, lds[px], fmaf(vw1, lds[4096 + px], fmaf(vw2, lds[8192 + px], vb))));
                s += u;
                if (i == 0) first = u;
                if (i == 63) last = u;
            }
            Fsh[g * 9 + 1 + task] = s;          // R0,R63,C0,C63
            if (task == 0) { Fsh[g * 9 + 5] = first; Fsh[g * 9 + 6] = last; }   // u00, u0_63
            if (task == 1) { Fsh[g * 9 + 7] = first; Fsh[g * 9 + 8] = last; }   // u63_0, u63_63
        }
        __syncthreads();  // everyone done reading t planes
        // S-reduce across the 16 q-chunks: padded stride 17 -> conflict-free
        #pragma unroll
        for (int j = 0; j < 4; ++j) lds[(gl + 32 * j) * 17 + q] = S[j];
    }
    __syncthreads();
    if (tid < 128) {
        float s = 0.f;
        #pragma unroll
        for (int qq = 0; qq < 16; ++qq) s += lds[tid * 17 + qq];
        Fsh[tid * 9 + 0] = s;
    }
    __syncthreads();
    {   // contract: m[b,g] = (1/4096) * sum_j w2e[j][g] * Fsh[j], 4 j-chunks
        int chunk = tid >> 7, g = tid & 127;
        float acc = 0.f;
        #pragma unroll 4
        for (int t = 0; t < 72; ++t) {
            int jb = chunk * 72 + t;
            float4 wvv = *(const float4*)&p.w2e[(size_t)jb * 512 + g * 4];
            float4 fv = *(const float4*)&Fsh[jb * 4];
            acc = fmaf(wvv.x, fv.x, fmaf(wvv.y, fv.y, fmaf(wvv.z, fv.z, fmaf(wvv.w, fv.w, acc))));
        }
        __syncthreads();
        lds[chunk * 128 + g] = acc;
    }
    __syncthreads();
    if (tid < 128)
        p.m[b * 128 + tid] = (lds[tid] + lds[128 + tid] + lds[256 + tid] + lds[384 + tid]) * (1.f / 4096.f);
    __threadfence();
    grid.sync();

    // ================= phase 4: bn3 + all heads =================
    {
        int g = tid & 127, quarter = tid >> 7;  // 0..3, 64 rows each
        float s = 0.f, s2 = 0.f;
        for (int i = 0; i < 64; ++i) {
            float v = p.m[(quarter * 64 + i) * 128 + g];
            s += v; s2 = fmaf(v, v, s2);
        }
        r8[quarter][g] = s; r8[4 + quarter][g] = s2;
    }
    __syncthreads();
    if (tid < 128) {
        float s = r8[0][tid] + r8[1][tid] + r8[2][tid] + r8[3][tid];
        float s2 = r8[4][tid] + r8[5][tid] + r8[6][tid] + r8[7][tid];
        float mean = s / 256.f, var = s2 / 256.f - mean * mean;
        float a = p.bn3_g[tid] * rsqrtf(var + EPSF);
        float bb = p.bn3_b[tid] - mean * a;
        xsh[tid] = fmaxf(0.f, fmaf(a, p.m[b * 128 + tid], bb));
    }
    // three LayerNorms, one per wave (waves 0..2 of the first 4)
    int l = ln, w = wv;
    if (w == 0) {  // agent LN(28)
        float av = (l < 28) ? p.agent[b * 28 + l] : 0.f;
        float s = wave_sum(av), s2 = wave_sum(av * av);
        s = __shfl(s, 0); s2 = __shfl(s2, 0);
        float mean = s / 28.f, var = s2 / 28.f - mean * mean;
        float rs = rsqrtf(var + EPSF);
        if (l < 28) lnv[l] = (av - mean) * rs * p.lnmig[l] + p.lnmib[l];
    } else if (w == 1) {  // actions build + LN(24)
        const float* abp = p.action + b * 15;
        float actv = 0.f;
        if (l < 24) {
            if (l < 4)       actv = abp[l];
            else if (l < 7)  { int ix = (int)abp[4];  actv = p.embc[ix * 3 + (l - 4)]; }
            else if (l < 10) { int ix = (int)abp[5];  actv = p.embe[ix * 3 + (l - 7)]; }
            else if (l < 13) actv = abp[l - 4];
            else if (l < 16) { int ix = (int)abp[9];  actv = p.embnc[ix * 3 + (l - 13)]; }
            else if (l < 18) { int ix = (int)abp[10]; actv = p.embns[ix * 2 + (l - 16)]; }
            else if (l < 21) { int ix = (int)abp[11]; actv = p.embp[ix * 3 + (l - 18)]; }
            else             actv = abp[l - 9];
        }
        float s = wave_sum(actv), s2 = wave_sum(actv * actv);
        s = __shfl(s, 0); s2 = __shfl(s2, 0);
        float mean = s / 24.f, var = s2 / 24.f - mean * mean;
        float rs = rsqrtf(var + EPSF);
        if (l < 24) lnca[l] = (actv - mean) * rs * p.lncag[l] + p.lncab[l];
    } else if (w == 2) {  // dist LN(56): sc = [zeros(28), agent]
        float g1v = (l < 56) ? p.agent[b * 28 + (l < 28 ? l : l - 28)] : 0.f;
        float av = (l < 28) ? g1v : 0.f;
        float s = wave_sum(av), s2 = wave_sum(av * av);
        s = __shfl(s, 0); s2 = __shfl(s2, 0);
        float mean = s / 56.f, var = s2 / 56.f - mean * mean;
        float rs = rsqrtf(var + EPSF);
        if (l < 56) {
            float vv = (l < 28) ? 0.f : g1v;
            lnsc[l] = (vv - mean) * rs * p.lndg[l] + p.lndb[l];
        }
    }
    __syncthreads();
    // first-layer neurons, thread-parallel
    if (tid < 100) {
        float a = 0.f;
        for (int i = 0; i < 28; ++i) a = fmaf(p.miw1[tid * 28 + i], lnv[i], a);
        h1[tid] = fmaxf(0.f, a);
    } else if (tid < 200) {
        int j = tid - 100;
        float a = p.cab1[j];
        for (int i = 0; i < 24; ++i) a = fmaf(p.caw1[j * 24 + i], lnca[i], a);
        h2[j] = fmaxf(0.f, a);
    } else if (tid < 250) {
        int j = tid - 200;
        float a = 0.f;
        for (int i = 0; i < 56; ++i) a = fmaf(p.dw1[j * 56 + i], lnsc[i], a);
        h3[j] = tanhf(a);
    }
    __syncthreads();
    // second layers + dist output
    if (tid < 20) {
        float a = 0.f;
        for (int i = 0; i < 100; ++i) a = fmaf(p.miw2[tid * 100 + i], h1[i], a);
        cat[20 + tid] = fmaxf(0.f, a);
    } else if (tid >= 64 && tid < 84) {
        int j = tid - 64;
        float a = p.cab2[j];
        for (int i = 0; i < 100; ++i) a = fmaf(p.caw2[j * 100 + i], h2[i], a);
        cat[40 + j] = fmaxf(0.f, a);
    } else if (tid >= 128 && tid < 148) {
        int j = tid - 128;
        float a = p.fc1b[j];
        for (int i = 0; i < 128; ++i) a = fmaf(p.fc1w[j * 128 + i], xsh[i], a);
        cat[j] = fmaxf(0.f, a);
    } else if (tid >= 192 && tid < 256) {
        int l3 = tid - 192;
        float dt = (l3 < 50) ? p.dw2[l3] * h3[l3] : 0.f;
        dt = wave_sum(dt);
        if (l3 == 0) p.out[256 + b] = tanhf(dt);
    }
    __syncthreads();
    // combined head LN(60) -> dot -> tanh (wave 0)
    if (w == 0) {
        float cv = (l < 60) ? cat[l] : 0.f;
        float ss = wave_sum(cv), ss2 = wave_sum(cv * cv);
        ss = __shfl(ss, 0); ss2 = __shfl(ss2, 0);
        float mean60 = ss / 60.f, var60 = ss2 / 60.f - mean60 * mean60;
        float rs60 = rsqrtf(var60 + EPSF);
        float term = (l < 60) ? p.cw[l] * ((cv - mean60) * rs60 * p.lncg[l] + p.lncb[l]) : 0.f;
        term = wave_sum(term);
        if (l == 0) p.out[b] = tanhf(term);
    }
}

extern "C" void kernel_launch(void* const* d_in, const int* in_sizes, int n_in,
                              void* d_out, int out_size, void* d_ws, size_t ws_size,
                              hipStream_t stream) {
    (void)in_sizes; (void)n_in; (void)out_size; (void)ws_size;
    float* ws = (float*)d_ws;
    Prm p;
    p.agent  = (const float*)d_in[0];
    p.world  = (const float*)d_in[1];
    p.action = (const float*)d_in[2];
    p.bn1_g  = (const float*)d_in[3];
    p.bn1_b  = (const float*)d_in[4];
    p.conv1w = (const float*)d_in[5];
    p.bn2_g  = (const float*)d_in[6];
    p.bn2_b  = (const float*)d_in[7];
    p.conv2w = (const float*)d_in[8];
    p.bn3_g  = (const float*)d_in[9];
    p.bn3_b  = (const float*)d_in[10];
    p.fc1w   = (const float*)d_in[11];
    p.fc1b   = (const float*)d_in[12];
    p.lnmig  = (const float*)d_in[13];
    p.lnmib  = (const float*)d_in[14];
    p.miw1   = (const float*)d_in[15];
    p.miw2   = (const float*)d_in[16];
    p.embc   = (const float*)d_in[17];
    p.embe   = (const float*)d_in[18];
    p.embnc  = (const float*)d_in[19];
    p.embns  = (const float*)d_in[20];
    p.embp   = (const float*)d_in[21];
    p.lncag  = (const float*)d_in[22];
    p.lncab  = (const float*)d_in[23];
    p.caw1   = (const float*)d_in[24];
    p.cab1   = (const float*)d_in[25];
    p.caw2   = (const float*)d_in[26];
    p.cab2   = (const float*)d_in[27];
    p.lncg   = (const float*)d_in[28];
    p.lncb   = (const float*)d_in[29];
    p.cw     = (const float*)d_in[30];
    p.lndg   = (const float*)d_in[31];
    p.lndb   = (const float*)d_in[32];
    p.dw1    = (const float*)d_in[33];
    p.dw2    = (const float*)d_in[34];
    p.red1 = ws + OFF_RED1;
    p.red2 = ws + OFF_RED2;
    p.w2e  = ws + OFF_W2E;
    p.m    = ws + OFF_M;
    p.out  = (float*)d_out;

    void* args[] = { &p };
    hipLaunchCooperativeKernel((void*)kAll, dim3(256), dim3(512), args, 0, stream);
}

// Round 5
// 190.532 us; speedup vs baseline: 2.2455x; 2.2455x over previous
//
#include <hip/hip_runtime.h>
#include <math.h>

#define EPSF 1e-5f

// B=256, C=3, H=W=64 (HW=4096), G=128
// ws layout (float offsets)
constexpr int OFF_RED1 = 0;        // 192*2  bn1 partials (sum,sumsq)
constexpr int OFF_A1B1 = 384;      // 6      folded bn1 affine a[3],b[3] (written by kB blk0)
constexpr int OFF_RED2 = 512;      // 256*9  t-moment partials
constexpr int OFF_W2E  = 4096;     // 128*128*9 effective conv2 weights
constexpr int OFF_M0   = OFF_W2E + 128 * 128 * 9;  // 256*128 partial m (g-half 0)
constexpr int OFF_M1   = OFF_M0 + 256 * 128;       // 256*128 partial m (g-half 1)

__device__ __forceinline__ float wave_sum(float v) {
    #pragma unroll
    for (int off = 32; off > 0; off >>= 1) v += __shfl_down(v, off);
    return v;
}

// ---------- kA: bn1 partial stats (blocks 0..191) + effective conv2 weights (192..255) ----------
__global__ __launch_bounds__(256) void kA(const float* __restrict__ x,
                                          const float* __restrict__ w2,
                                          float* __restrict__ red1,
                                          float* __restrict__ w2e) {
    int blk = blockIdx.x, tid = threadIdx.x;
    if (blk < 192) {
        int c = blk % 3, seg = blk / 3;  // 64 segs x 4 b
        float s = 0.f, s2 = 0.f;
        for (int bb = 0; bb < 4; ++bb) {
            int b = seg * 4 + bb;
            const float4* p = (const float4*)(x + (size_t)(b * 3 + c) * 4096);
            for (int i = tid; i < 1024; i += 256) {
                float4 v = p[i];
                s += v.x + v.y + v.z + v.w;
                s2 = fmaf(v.x, v.x, s2); s2 = fmaf(v.y, v.y, s2);
                s2 = fmaf(v.z, v.z, s2); s2 = fmaf(v.w, v.w, s2);
            }
        }
        __shared__ float ls[4], ls2[4];
        float ws_ = wave_sum(s), ws2_ = wave_sum(s2);
        if ((tid & 63) == 0) { ls[tid >> 6] = ws_; ls2[tid >> 6] = ws2_; }
        __syncthreads();
        if (tid == 0) {
            red1[blk * 2 + 0] = ls[0] + ls[1] + ls[2] + ls[3];
            red1[blk * 2 + 1] = ls2[0] + ls2[1] + ls2[2] + ls2[3];
        }
    } else {
        // effective conv2 weights: feature order S,R0,R63,C0,C63,u00,u0_63,u63_0,u63_63
        int idx = (blk - 192) * 256 + tid;  // 16384 (g,g') pairs
        int g = idx >> 7, gp = idx & 127;
        const float* wp = w2 + (size_t)(g * 128 + gp) * 9;  // [ky][kx]
        float v0 = wp[0], v1 = wp[1], v2 = wp[2], v3 = wp[3], v4 = wp[4],
              v5 = wp[5], v6 = wp[6], v7 = wp[7], v8 = wp[8];
        float c[9];
        c[0] = ((v0 + v1) + (v2 + v3)) + ((v4 + v5) + (v6 + v7)) + v8;
        c[1] = -(v6 + v7 + v8);
        c[2] = -(v0 + v1 + v2);
        c[3] = -(v2 + v5 + v8);
        c[4] = -(v0 + v3 + v6);
        c[5] = v8; c[6] = v6; c[7] = v2; c[8] = v0;
        #pragma unroll
        for (int k = 0; k < 9; ++k) {
            int jj = gp * 9 + k;                                     // 0..1151
            w2e[(size_t)(jj >> 2) * 512 + g * 4 + (jj & 3)] = c[k];  // [jblk][g][4]
        }
    }
}

// ---------- kB: in-block bn1 finalize + per-b 3x3 second moments of t = relu(bn1(x)) ----------
__global__ __launch_bounds__(256) void kB(const float* __restrict__ x,
                                          const float* __restrict__ red1,
                                          const float* __restrict__ g1,
                                          const float* __restrict__ b1,
                                          float* __restrict__ red2,
                                          float* __restrict__ a1b1) {
    __shared__ float ab[6];
    int b = blockIdx.x, tid = threadIdx.x;
    if (tid < 3) {
        float s = 0.f, s2 = 0.f;
        for (int seg = 0; seg < 64; ++seg) {
            s  += red1[(seg * 3 + tid) * 2 + 0];
            s2 += red1[(seg * 3 + tid) * 2 + 1];
        }
        float n = 256.f * 4096.f;
        float mean = s / n, var = s2 / n - mean * mean;
        float a = g1[tid] * rsqrtf(var + EPSF);
        ab[tid] = a; ab[3 + tid] = b1[tid] - mean * a;
        if (b == 0) { a1b1[tid] = a; a1b1[3 + tid] = ab[3 + tid]; }
    }
    __syncthreads();
    float A0 = ab[0], A1 = ab[1], A2 = ab[2];
    float B0 = ab[3], B1 = ab[4], B2 = ab[5];
    float acc[9] = {0, 0, 0, 0, 0, 0, 0, 0, 0};
    const float4* p0 = (const float4*)(x + (size_t)(b * 3 + 0) * 4096);
    const float4* p1 = (const float4*)(x + (size_t)(b * 3 + 1) * 4096);
    const float4* p2 = (const float4*)(x + (size_t)(b * 3 + 2) * 4096);
    for (int i = tid; i < 1024; i += 256) {
        float4 v0 = p0[i], v1 = p1[i], v2 = p2[i];
        #define MOM(e) { \
            float t0 = fmaxf(0.f, fmaf(A0, v0.e, B0)); \
            float t1 = fmaxf(0.f, fmaf(A1, v1.e, B1)); \
            float t2 = fmaxf(0.f, fmaf(A2, v2.e, B2)); \
            acc[0] += t0; acc[1] += t1; acc[2] += t2; \
            acc[3] = fmaf(t0, t0, acc[3]); acc[4] = fmaf(t0, t1, acc[4]); \
            acc[5] = fmaf(t0, t2, acc[5]); acc[6] = fmaf(t1, t1, acc[6]); \
            acc[7] = fmaf(t1, t2, acc[7]); acc[8] = fmaf(t2, t2, acc[8]); }
        MOM(x) MOM(y) MOM(z) MOM(w)
        #undef MOM
    }
    __shared__ float lw[4][9];
    #pragma unroll
    for (int k = 0; k < 9; ++k) {
        float v = wave_sum(acc[k]);
        if ((tid & 63) == 0) lw[tid >> 6][k] = v;
    }
    __syncthreads();
    if (tid == 0) {
        #pragma unroll
        for (int k = 0; k < 9; ++k)
            red2[b * 9 + k] = lw[0][k] + lw[1][k] + lw[2][k] + lw[3][k];
    }
}

// ---------- kC: 512 blocks (b x g-half) x 256 thr, ~54KB LDS -> 2 blocks/CU ----------
// Each block: bn2 fold for its 64 g's + S hot loop (j=8, bank-staggered) +
// boundary pass + partial contract over its 576 F entries -> m_part[h][b][g'].
__global__ __launch_bounds__(256) void kC(const float* __restrict__ x,
                                          const float* __restrict__ red2,
                                          const float* __restrict__ w1,
                                          const float* __restrict__ g2,
                                          const float* __restrict__ b2,
                                          const float* __restrict__ a1b1,
                                          const float* __restrict__ w2e,
                                          float* __restrict__ mp0,
                                          float* __restrict__ mp1) {
    __shared__ __align__(16) float lds[12288];  // t planes; reused for S-reduce + contract partials
    __shared__ __align__(16) float Fsh[576];    // this block's 64 g x 9 features
    __shared__ float wt[192], bt[64], momp[144], mom[9], ab[6];
    int b = blockIdx.x >> 1, h = blockIdx.x & 1, tid = threadIdx.x;
    if (tid < 6) ab[tid] = a1b1[tid];
    if (tid >= 64 && tid < 208) {  // momp: 16 segs x 9 moments, 16 rows each
        int t = tid - 64;
        int seg = t / 9, k = t - seg * 9;
        float s = 0.f;
        #pragma unroll
        for (int r = 0; r < 16; ++r) s += red2[(seg * 16 + r) * 9 + k];
        momp[t] = s;
    }
    __syncthreads();
    if (tid < 9) {
        float s = 0.f;
        #pragma unroll
        for (int sg = 0; sg < 16; ++sg) s += momp[sg * 9 + tid];
        mom[tid] = s / (256.f * 4096.f);
    }
    // stage t planes (ab ready)
    {
        float A0 = ab[0], A1 = ab[1], A2 = ab[2];
        float B0 = ab[3], B1 = ab[4], B2 = ab[5];
        const float4* xb = (const float4*)(x + (size_t)b * 12288);
        #pragma unroll
        for (int k = 0; k < 12; ++k) {
            int i = k * 256 + tid;
            float4 v = xb[i];
            float a = (k < 4) ? A0 : ((k < 8) ? A1 : A2);
            float bb = (k < 4) ? B0 : ((k < 8) ? B1 : B2);
            v.x = fmaxf(0.f, fmaf(a, v.x, bb));
            v.y = fmaxf(0.f, fmaf(a, v.y, bb));
            v.z = fmaxf(0.f, fmaf(a, v.z, bb));
            v.w = fmaxf(0.f, fmaf(a, v.w, bb));
            *(float4*)&lds[i << 2] = v;
        }
    }
    __syncthreads();
    if (tid < 64) {  // bn2 fold for this block's 64 g's
        int g = h * 64 + tid;
        float wa = w1[g * 3 + 0], wb = w1[g * 3 + 1], wc = w1[g * 3 + 2];
        float mean = wa * mom[0] + wb * mom[1] + wc * mom[2];
        float ey2 = wa * wa * mom[3] + wb * wb * mom[6] + wc * wc * mom[8]
                  + 2.f * (wa * wb * mom[4] + wa * wc * mom[5] + wb * wc * mom[7]);
        float var = ey2 - mean * mean;
        float a = g2[g] * rsqrtf(var + EPSF);
        wt[tid * 3 + 0] = a * wa; wt[tid * 3 + 1] = a * wb; wt[tid * 3 + 2] = a * wc;
        bt[tid] = b2[g] - mean * a;
    }
    __syncthreads();
    // ---- hot loop: j=8 g's/thread, 32 px-chunks of 128 px, bank-staggered ----
    int gl = tid & 7, q = tid >> 3;  // q 0..31
    {
        float w0[8], w1v[8], w2v[8], bw[8], S[8];
        #pragma unroll
        for (int j = 0; j < 8; ++j) {
            int g = gl + 8 * j;
            w0[j] = wt[g * 3 + 0]; w1v[j] = wt[g * 3 + 1];
            w2v[j] = wt[g * 3 + 2]; bw[j] = bt[g];
            S[j] = 0.f;
        }
        int stag = (q & 7) * 4;
        #pragma unroll 4
        for (int i = 0; i < 32; ++i) {
            int ie = (i + stag) & 31;
            int px = q * 128 + ie * 4;
            float4 t0 = *(const float4*)&lds[px];
            float4 t1 = *(const float4*)&lds[4096 + px];
            float4 t2 = *(const float4*)&lds[8192 + px];
            #pragma unroll
            for (int j = 0; j < 8; ++j) {
                float u0 = fmaxf(0.f, fmaf(w0[j], t0.x, fmaf(w1v[j], t1.x, fmaf(w2v[j], t2.x, bw[j]))));
                float u1 = fmaxf(0.f, fmaf(w0[j], t0.y, fmaf(w1v[j], t1.y, fmaf(w2v[j], t2.y, bw[j]))));
                float u2 = fmaxf(0.f, fmaf(w0[j], t0.z, fmaf(w1v[j], t1.z, fmaf(w2v[j], t2.z, bw[j]))));
                float u3 = fmaxf(0.f, fmaf(w0[j], t0.w, fmaf(w1v[j], t1.w, fmaf(w2v[j], t2.w, bw[j]))));
                S[j] += (u0 + u1) + (u2 + u3);
            }
        }
        // ---- boundary post-pass: 64 g x 4 tasks, one thread each ----
        {
            int g = tid & 63, task = tid >> 6;
            float vw0 = wt[g * 3 + 0], vw1 = wt[g * 3 + 1], vw2 = wt[g * 3 + 2], vb = bt[g];
            float s = 0.f, first = 0.f, last = 0.f;
            int p0 = (task == 1) ? 63 * 64 : ((task == 3) ? 63 : 0);
            int stp = (task >= 2) ? 64 : 1;
            #pragma unroll 4
            for (int i = 0; i < 64; ++i) {
                int px = p0 + i * stp;
                float u = fmaxf(0.f, fmaf(vw0, lds[px], fmaf(vw1, lds[4096 + px], fmaf(vw2, lds[8192 + px], vb))));
                s += u;
                if (i == 0) first = u;
                if (i == 63) last = u;
            }
            Fsh[g * 9 + 1 + task] = s;          // R0,R63,C0,C63
            if (task == 0) { Fsh[g * 9 + 5] = first; Fsh[g * 9 + 6] = last; }   // u00, u0_63
            if (task == 1) { Fsh[g * 9 + 7] = first; Fsh[g * 9 + 8] = last; }   // u63_0, u63_63
        }
        __syncthreads();  // everyone done reading t planes
        // S-reduce across the 32 q-chunks: padded stride 33 -> (near) conflict-free
        #pragma unroll
        for (int j = 0; j < 8; ++j) lds[(gl + 8 * j) * 33 + q] = S[j];
    }
    __syncthreads();
    if (tid < 64) {
        float s = 0.f;
        #pragma unroll
        for (int qq = 0; qq < 32; ++qq) s += lds[tid * 33 + qq];
        Fsh[tid * 9 + 0] = s;
    }
    __syncthreads();
    // partial contract: pm[g'] = sum over this block's 144 j-blocks of w2e[jb][g'].F[jb]
    {
        int chunk = tid >> 7, g = tid & 127;  // 2 chunks x 72 j-blocks
        float acc = 0.f;
        int jb0 = h * 144 + chunk * 72;
        #pragma unroll 4
        for (int t = 0; t < 72; ++t) {
            int jb = jb0 + t;
            float4 wv = *(const float4*)&w2e[(size_t)jb * 512 + g * 4];
            float4 fv = *(const float4*)&Fsh[(chunk * 72 + t) * 4];
            acc = fmaf(wv.x, fv.x, fmaf(wv.y, fv.y, fmaf(wv.z, fv.z, fmaf(wv.w, fv.w, acc))));
        }
        __syncthreads();
        lds[chunk * 128 + g] = acc;
    }
    __syncthreads();
    if (tid < 128) {
        float* mp = h ? mp1 : mp0;
        mp[b * 128 + tid] = (lds[tid] + lds[128 + tid]) * (1.f / 4096.f);
    }
}

// ---------- kE: bn3 (redundant per-block batch stats over mp0+mp1) + all heads ----------
__global__ __launch_bounds__(256) void kE(
    const float* __restrict__ mp0, const float* __restrict__ mp1,
    const float* __restrict__ g3, const float* __restrict__ b3,
    const float* __restrict__ agent, const float* __restrict__ action,
    const float* __restrict__ fc1w, const float* __restrict__ fc1b,
    const float* __restrict__ lnmig, const float* __restrict__ lnmib,
    const float* __restrict__ miw1, const float* __restrict__ miw2,
    const float* __restrict__ embc, const float* __restrict__ embe,
    const float* __restrict__ embnc, const float* __restrict__ embns,
    const float* __restrict__ embp,
    const float* __restrict__ lncag, const float* __restrict__ lncab,
    const float* __restrict__ caw1, const float* __restrict__ cab1,
    const float* __restrict__ caw2, const float* __restrict__ cab2,
    const float* __restrict__ lncg, const float* __restrict__ lncb,
    const float* __restrict__ cw,
    const float* __restrict__ lndg, const float* __restrict__ lndb,
    const float* __restrict__ dw1, const float* __restrict__ dw2,
    float* __restrict__ out) {
    __shared__ float red[4][128];
    __shared__ float xsh[128];
    __shared__ float lnv[28], lnca[24], lnsc[56], h1[100], h2[100], h3[50], cat[60];
    int b = blockIdx.x, tid = threadIdx.x;
    // bn3 batch stats (each block redundantly; mp is 256KB, L2-hot)
    {
        int g = tid & 127, half = tid >> 7;
        float s = 0.f, s2 = 0.f;
        for (int i = 0; i < 128; ++i) {
            int idx = (half * 128 + i) * 128 + g;
            float v = mp0[idx] + mp1[idx];
            s += v; s2 = fmaf(v, v, s2);
        }
        red[half * 2 + 0][g] = s;
        red[half * 2 + 1][g] = s2;
    }
    __syncthreads();
    if (tid < 128) {
        float s = red[0][tid] + red[2][tid], s2 = red[1][tid] + red[3][tid];
        float mean = s / 256.f, var = s2 / 256.f - mean * mean;
        float a = g3[tid] * rsqrtf(var + EPSF);
        float bb = b3[tid] - mean * a;
        float mv = mp0[b * 128 + tid] + mp1[b * 128 + tid];
        xsh[tid] = fmaxf(0.f, fmaf(a, mv, bb));
    }
    // phase B: three LayerNorms, one per wave
    int l = tid & 63, w = tid >> 6;
    if (w == 0) {  // agent LN(28)
        float av = (l < 28) ? agent[b * 28 + l] : 0.f;
        float s = wave_sum(av), s2 = wave_sum(av * av);
        s = __shfl(s, 0); s2 = __shfl(s2, 0);
        float mean = s / 28.f, var = s2 / 28.f - mean * mean;
        float rs = rsqrtf(var + EPSF);
        if (l < 28) lnv[l] = (av - mean) * rs * lnmig[l] + lnmib[l];
    } else if (w == 1) {  // actions build + LN(24)
        const float* ab = action + b * 15;
        float actv = 0.f;
        if (l < 24) {
            if (l < 4)       actv = ab[l];
            else if (l < 7)  { int ix = (int)ab[4];  actv = embc[ix * 3 + (l - 4)]; }
            else if (l < 10) { int ix = (int)ab[5];  actv = embe[ix * 3 + (l - 7)]; }
            else if (l < 13) actv = ab[l - 4];
            else if (l < 16) { int ix = (int)ab[9];  actv = embnc[ix * 3 + (l - 13)]; }
            else if (l < 18) { int ix = (int)ab[10]; actv = embns[ix * 2 + (l - 16)]; }
            else if (l < 21) { int ix = (int)ab[11]; actv = embp[ix * 3 + (l - 18)]; }
            else             actv = ab[l - 9];
        }
        float s = wave_sum(actv), s2 = wave_sum(actv * actv);
        s = __shfl(s, 0); s2 = __shfl(s2, 0);
        float mean = s / 24.f, var = s2 / 24.f - mean * mean;
        float rs = rsqrtf(var + EPSF);
        if (l < 24) lnca[l] = (actv - mean) * rs * lncag[l] + lncab[l];
    } else if (w == 2) {  // dist LN(56): sc = [zeros(28), agent]
        float g1v = (l < 56) ? agent[b * 28 + (l < 28 ? l : l - 28)] : 0.f;
        float av = (l < 28) ? g1v : 0.f;
        float s = wave_sum(av), s2 = wave_sum(av * av);
        s = __shfl(s, 0); s2 = __shfl(s2, 0);
        float mean = s / 56.f, var = s2 / 56.f - mean * mean;
        float rs = rsqrtf(var + EPSF);
        if (l < 56) {
            float vv = (l < 28) ? 0.f : g1v;
            lnsc[l] = (vv - mean) * rs * lndg[l] + lndb[l];
        }
    }
    __syncthreads();
    // phase C: first-layer neurons, thread-parallel
    if (tid < 100) {
        float a = 0.f;
        for (int i = 0; i < 28; ++i) a = fmaf(miw1[tid * 28 + i], lnv[i], a);
        h1[tid] = fmaxf(0.f, a);
    } else if (tid < 200) {
        int j = tid - 100;
        float a = cab1[j];
        for (int i = 0; i < 24; ++i) a = fmaf(caw1[j * 24 + i], lnca[i], a);
        h2[j] = fmaxf(0.f, a);
    } else if (tid < 250) {
        int j = tid - 200;
        float a = 0.f;
        for (int i = 0; i < 56; ++i) a = fmaf(dw1[j * 56 + i], lnsc[i], a);
        h3[j] = tanhf(a);
    }
    __syncthreads();
    // phase D: second layers + dist output
    if (tid < 20) {
        float a = 0.f;
        for (int i = 0; i < 100; ++i) a = fmaf(miw2[tid * 100 + i], h1[i], a);
        cat[20 + tid] = fmaxf(0.f, a);
    } else if (tid >= 64 && tid < 84) {
        int j = tid - 64;
        float a = cab2[j];
        for (int i = 0; i < 100; ++i) a = fmaf(caw2[j * 100 + i], h2[i], a);
        cat[40 + j] = fmaxf(0.f, a);
    } else if (tid >= 128 && tid < 148) {
        int j = tid - 128;
        float a = fc1b[j];
        for (int i = 0; i < 128; ++i) a = fmaf(fc1w[j * 128 + i], xsh[i], a);
        cat[j] = fmaxf(0.f, a);
    } else if (tid >= 192) {
        int l3 = tid - 192;
        float dt = (l3 < 50) ? dw2[l3] * h3[l3] : 0.f;
        dt = wave_sum(dt);
        if (l3 == 0) out[256 + b] = tanhf(dt);
    }
    __syncthreads();
    // phase E: combined head LN(60) -> dot -> tanh (wave 0)
    if (w == 0) {
        float cv = (l < 60) ? cat[l] : 0.f;
        float ss = wave_sum(cv), ss2 = wave_sum(cv * cv);
        ss = __shfl(ss, 0); ss2 = __shfl(ss2, 0);
        float mean60 = ss / 60.f, var60 = ss2 / 60.f - mean60 * mean60;
        float rs60 = rsqrtf(var60 + EPSF);
        float term = (l < 60) ? cw[l] * ((cv - mean60) * rs60 * lncg[l] + lncb[l]) : 0.f;
        term = wave_sum(term);
        if (l == 0) out[b] = tanhf(term);
    }
}

extern "C" void kernel_launch(void* const* d_in, const int* in_sizes, int n_in,
                              void* d_out, int out_size, void* d_ws, size_t ws_size,
                              hipStream_t stream) {
    (void)in_sizes; (void)n_in; (void)out_size; (void)ws_size;
    const float* agent  = (const float*)d_in[0];
    const float* world  = (const float*)d_in[1];
    const float* action = (const float*)d_in[2];
    const float* bn1_g  = (const float*)d_in[3];
    const float* bn1_b  = (const float*)d_in[4];
    const float* conv1w = (const float*)d_in[5];
    const float* bn2_g  = (const float*)d_in[6];
    const float* bn2_b  = (const float*)d_in[7];
    const float* conv2w = (const float*)d_in[8];
    const float* bn3_g  = (const float*)d_in[9];
    const float* bn3_b  = (const float*)d_in[10];
    const float* fc1w   = (const float*)d_in[11];
    const float* fc1b   = (const float*)d_in[12];
    const float* lnmig  = (const float*)d_in[13];
    const float* lnmib  = (const float*)d_in[14];
    const float* miw1   = (const float*)d_in[15];
    const float* miw2   = (const float*)d_in[16];
    const float* embc   = (const float*)d_in[17];
    const float* embe   = (const float*)d_in[18];
    const float* embnc  = (const float*)d_in[19];
    const float* embns  = (const float*)d_in[20];
    const float* embp   = (const float*)d_in[21];
    const float* lncag  = (const float*)d_in[22];
    const float* lncab  = (const float*)d_in[23];
    const float* caw1   = (const float*)d_in[24];
    const float* cab1   = (const float*)d_in[25];
    const float* caw2   = (const float*)d_in[26];
    const float* cab2   = (const float*)d_in[27];
    const float* lncg   = (const float*)d_in[28];
    const float* lncb   = (const float*)d_in[29];
    const float* cw     = (const float*)d_in[30];
    const float* lndg   = (const float*)d_in[31];
    const float* lndb   = (const float*)d_in[32];
    const float* dw1    = (const float*)d_in[33];
    const float* dw2    = (const float*)d_in[34];
    float* out = (float*)d_out;
    float* ws = (float*)d_ws;

    hipLaunchKernelGGL(kA, dim3(256), dim3(256), 0, stream,
                       world, conv2w, ws + OFF_RED1, ws + OFF_W2E);
    hipLaunchKernelGGL(kB, dim3(256), dim3(256), 0, stream,
                       world, ws + OFF_RED1, bn1_g, bn1_b, ws + OFF_RED2, ws + OFF_A1B1);
    hipLaunchKernelGGL(kC, dim3(512), dim3(256), 0, stream,
                       world, ws + OFF_RED2, conv1w, bn2_g, bn2_b, ws + OFF_A1B1,
                       ws + OFF_W2E, ws + OFF_M0, ws + OFF_M1);
    hipLaunchKernelGGL(kE, dim3(256), dim3(256), 0, stream,
                       ws + OFF_M0, ws + OFF_M1, bn3_g, bn3_b, agent, action, fc1w, fc1b,
                       lnmig, lnmib, miw1, miw2,
                       embc, embe, embnc, embns, embp,
                       lncag, lncab, caw1, cab1, caw2, cab2,
                       lncg, lncb, cw, lndg, lndb, dw1, dw2, out);
}

// Round 6
// 188.768 us; speedup vs baseline: 2.2664x; 1.0093x over previous
//
#include <hip/hip_runtime.h>
#include <math.h>

#define EPSF 1e-5f

// B=256, C=3, H=W=64 (HW=4096), G=128
// ws layout (float offsets)
constexpr int OFF_RED1 = 0;        // 192*2  bn1 partials (sum,sumsq)
constexpr int OFF_A1B1 = 384;      // 6      folded bn1 affine a[3],b[3] (written by kB blk0)
constexpr int OFF_RED2 = 512;      // 256*9  t-moment partials
constexpr int OFF_W2E  = 4096;     // 128*128*9 effective conv2 weights
constexpr int OFF_M    = OFF_W2E + 128 * 128 * 9;  // 256*128 pooled conv2 output

__device__ __forceinline__ float wave_sum(float v) {
    #pragma unroll
    for (int off = 32; off > 0; off >>= 1) v += __shfl_down(v, off);
    return v;
}

// VOP3P packed fp32 (2 FMAs / 2 adds per instruction) — compiler won't form these
// from scalar code; "v" on float2 maps to an aligned VGPR pair.
__device__ __forceinline__ float2 pk_fma(float2 a, float2 b, float2 c) {
    float2 d;
    asm("v_pk_fma_f32 %0, %1, %2, %3" : "=v"(d) : "v"(a), "v"(b), "v"(c));
    return d;
}
__device__ __forceinline__ float2 pk_add(float2 a, float2 b) {
    float2 d;
    asm("v_pk_add_f32 %0, %1, %2" : "=v"(d) : "v"(a), "v"(b));
    return d;
}

// ---------- kA: bn1 partial stats (blocks 0..191) + effective conv2 weights (192..255) ----------
__global__ __launch_bounds__(256) void kA(const float* __restrict__ x,
                                          const float* __restrict__ w2,
                                          float* __restrict__ red1,
                                          float* __restrict__ w2e) {
    int blk = blockIdx.x, tid = threadIdx.x;
    if (blk < 192) {
        int c = blk % 3, seg = blk / 3;  // 64 segs x 4 b
        float s = 0.f, s2 = 0.f;
        for (int bb = 0; bb < 4; ++bb) {
            int b = seg * 4 + bb;
            const float4* p = (const float4*)(x + (size_t)(b * 3 + c) * 4096);
            for (int i = tid; i < 1024; i += 256) {
                float4 v = p[i];
                s += v.x + v.y + v.z + v.w;
                s2 = fmaf(v.x, v.x, s2); s2 = fmaf(v.y, v.y, s2);
                s2 = fmaf(v.z, v.z, s2); s2 = fmaf(v.w, v.w, s2);
            }
        }
        __shared__ float ls[4], ls2[4];
        float ws_ = wave_sum(s), ws2_ = wave_sum(s2);
        if ((tid & 63) == 0) { ls[tid >> 6] = ws_; ls2[tid >> 6] = ws2_; }
        __syncthreads();
        if (tid == 0) {
            red1[blk * 2 + 0] = ls[0] + ls[1] + ls[2] + ls[3];
            red1[blk * 2 + 1] = ls2[0] + ls2[1] + ls2[2] + ls2[3];
        }
    } else {
        // effective conv2 weights: feature order S,R0,R63,C0,C63,u00,u0_63,u63_0,u63_63
        int idx = (blk - 192) * 256 + tid;  // 16384 (g,g') pairs
        int g = idx >> 7, gp = idx & 127;
        const float* wp = w2 + (size_t)(g * 128 + gp) * 9;  // [ky][kx]
        float v0 = wp[0], v1 = wp[1], v2 = wp[2], v3 = wp[3], v4 = wp[4],
              v5 = wp[5], v6 = wp[6], v7 = wp[7], v8 = wp[8];
        float c[9];
        c[0] = ((v0 + v1) + (v2 + v3)) + ((v4 + v5) + (v6 + v7)) + v8;
        c[1] = -(v6 + v7 + v8);
        c[2] = -(v0 + v1 + v2);
        c[3] = -(v2 + v5 + v8);
        c[4] = -(v0 + v3 + v6);
        c[5] = v8; c[6] = v6; c[7] = v2; c[8] = v0;
        #pragma unroll
        for (int k = 0; k < 9; ++k) {
            int jj = gp * 9 + k;                                     // 0..1151
            w2e[(size_t)(jj >> 2) * 512 + g * 4 + (jj & 3)] = c[k];  // [jblk][g][4]
        }
    }
}

// ---------- kB: in-block bn1 finalize + per-b 3x3 second moments of t = relu(bn1(x)) ----------
__global__ __launch_bounds__(256) void kB(const float* __restrict__ x,
                                          const float* __restrict__ red1,
                                          const float* __restrict__ g1,
                                          const float* __restrict__ b1,
                                          float* __restrict__ red2,
                                          float* __restrict__ a1b1) {
    __shared__ float ab[6];
    int b = blockIdx.x, tid = threadIdx.x;
    if (tid < 3) {
        float s = 0.f, s2 = 0.f;
        for (int seg = 0; seg < 64; ++seg) {
            s  += red1[(seg * 3 + tid) * 2 + 0];
            s2 += red1[(seg * 3 + tid) * 2 + 1];
        }
        float n = 256.f * 4096.f;
        float mean = s / n, var = s2 / n - mean * mean;
        float a = g1[tid] * rsqrtf(var + EPSF);
        ab[tid] = a; ab[3 + tid] = b1[tid] - mean * a;
        if (b == 0) { a1b1[tid] = a; a1b1[3 + tid] = ab[3 + tid]; }
    }
    __syncthreads();
    float A0 = ab[0], A1 = ab[1], A2 = ab[2];
    float B0 = ab[3], B1 = ab[4], B2 = ab[5];
    float acc[9] = {0, 0, 0, 0, 0, 0, 0, 0, 0};
    const float4* p0 = (const float4*)(x + (size_t)(b * 3 + 0) * 4096);
    const float4* p1 = (const float4*)(x + (size_t)(b * 3 + 1) * 4096);
    const float4* p2 = (const float4*)(x + (size_t)(b * 3 + 2) * 4096);
    for (int i = tid; i < 1024; i += 256) {
        float4 v0 = p0[i], v1 = p1[i], v2 = p2[i];
        #define MOM(e) { \
            float t0 = fmaxf(0.f, fmaf(A0, v0.e, B0)); \
            float t1 = fmaxf(0.f, fmaf(A1, v1.e, B1)); \
            float t2 = fmaxf(0.f, fmaf(A2, v2.e, B2)); \
            acc[0] += t0; acc[1] += t1; acc[2] += t2; \
            acc[3] = fmaf(t0, t0, acc[3]); acc[4] = fmaf(t0, t1, acc[4]); \
            acc[5] = fmaf(t0, t2, acc[5]); acc[6] = fmaf(t1, t1, acc[6]); \
            acc[7] = fmaf(t1, t2, acc[7]); acc[8] = fmaf(t2, t2, acc[8]); }
        MOM(x) MOM(y) MOM(z) MOM(w)
        #undef MOM
    }
    __shared__ float lw[4][9];
    #pragma unroll
    for (int k = 0; k < 9; ++k) {
        float v = wave_sum(acc[k]);
        if ((tid & 63) == 0) lw[tid >> 6][k] = v;
    }
    __syncthreads();
    if (tid == 0) {
        #pragma unroll
        for (int k = 0; k < 9; ++k)
            red2[b * 9 + k] = lw[0][k] + lw[1][k] + lw[2][k] + lw[3][k];
    }
}

// ---------- kC: bn2 fold + boundary features + contract -> m[b,:] (R3 structure, packed hot loop) ----------
__global__ __launch_bounds__(512) void kC(const float* __restrict__ x,
                                          const float* __restrict__ red2,
                                          const float* __restrict__ w1,
                                          const float* __restrict__ g2,
                                          const float* __restrict__ b2,
                                          const float* __restrict__ a1b1,
                                          const float* __restrict__ w2e,
                                          float* __restrict__ m) {
    __shared__ __align__(16) float lds[12288];  // t planes; reused for S-reduce + contract partials
    __shared__ __align__(16) float Fsh[1152];
    __shared__ float wt[384], bt[128], momp[288], mom[9], ab[6];
    int b = blockIdx.x, tid = threadIdx.x;
    if (tid < 6) ab[tid] = a1b1[tid];
    if (tid < 288) {  // 32 segs x 9 moments, 8 rows each — independent loads
        int seg = tid / 9, k = tid - seg * 9;
        float s = 0.f;
        #pragma unroll
        for (int r = 0; r < 8; ++r) s += red2[(seg * 8 + r) * 9 + k];
        momp[tid] = s;
    }
    __syncthreads();
    if (tid < 9) {
        float s = 0.f;
        #pragma unroll
        for (int sg = 0; sg < 32; ++sg) s += momp[sg * 9 + tid];
        mom[tid] = s / (256.f * 4096.f);
    }
    // stage t planes (ab ready — barrier above)
    {
        float A0 = ab[0], A1 = ab[1], A2 = ab[2];
        float B0 = ab[3], B1 = ab[4], B2 = ab[5];
        const float4* xb = (const float4*)(x + (size_t)b * 3 * 4096);
        for (int i = tid; i < 3072; i += 512) {
            float4 v = xb[i];
            int c = i >> 10;
            float a = (c == 0) ? A0 : ((c == 1) ? A1 : A2);
            float bb = (c == 0) ? B0 : ((c == 1) ? B1 : B2);
            v.x = fmaxf(0.f, fmaf(a, v.x, bb));
            v.y = fmaxf(0.f, fmaf(a, v.y, bb));
            v.z = fmaxf(0.f, fmaf(a, v.z, bb));
            v.w = fmaxf(0.f, fmaf(a, v.w, bb));
            *(float4*)&lds[i << 2] = v;
        }
    }
    __syncthreads();
    if (tid < 128) {  // bn2 fold into conv1 weights
        int g = tid;
        float wa = w1[g * 3 + 0], wb = w1[g * 3 + 1], wc = w1[g * 3 + 2];
        float mean = wa * mom[0] + wb * mom[1] + wc * mom[2];
        float ey2 = wa * wa * mom[3] + wb * wb * mom[6] + wc * wc * mom[8]
                  + 2.f * (wa * wb * mom[4] + wa * wc * mom[5] + wb * wc * mom[7]);
        float var = ey2 - mean * mean;
        float a = g2[g] * rsqrtf(var + EPSF);
        wt[g * 3 + 0] = a * wa; wt[g * 3 + 1] = a * wb; wt[g * 3 + 2] = a * wc;
        bt[g] = b2[g] - mean * a;
    }
    __syncthreads();
    // ---- hot loop: full-plane S only, packed fp32 (v_pk_fma_f32) ----
    int gl = tid & 31, q = tid >> 5;  // 16 chunks x 256 pixels; 4 g's per thread
    {
        float2 w0p[4], w1p[4], w2p[4], bwp[4], Sp[4];
        #pragma unroll
        for (int j = 0; j < 4; ++j) {
            int g = gl + 32 * j;
            float a0 = wt[g * 3 + 0], a1 = wt[g * 3 + 1], a2 = wt[g * 3 + 2], bb = bt[g];
            w0p[j] = make_float2(a0, a0); w1p[j] = make_float2(a1, a1);
            w2p[j] = make_float2(a2, a2); bwp[j] = make_float2(bb, bb);
            Sp[j] = make_float2(0.f, 0.f);
        }
        int base = q * 256;
        #pragma unroll 4
        for (int i = 0; i < 64; ++i) {
            int pp = base + i * 4;
            float4 t0 = *(const float4*)&lds[pp];
            float4 t1 = *(const float4*)&lds[4096 + pp];
            float4 t2 = *(const float4*)&lds[8192 + pp];
            float2 t0a = make_float2(t0.x, t0.y), t0b = make_float2(t0.z, t0.w);
            float2 t1a = make_float2(t1.x, t1.y), t1b = make_float2(t1.z, t1.w);
            float2 t2a = make_float2(t2.x, t2.y), t2b = make_float2(t2.z, t2.w);
            #pragma unroll
            for (int j = 0; j < 4; ++j) {
                float2 da = pk_fma(w0p[j], t0a, bwp[j]);
                da = pk_fma(w1p[j], t1a, da);
                da = pk_fma(w2p[j], t2a, da);
                float2 db = pk_fma(w0p[j], t0b, bwp[j]);
                db = pk_fma(w1p[j], t1b, db);
                db = pk_fma(w2p[j], t2b, db);
                da.x = fmaxf(da.x, 0.f); da.y = fmaxf(da.y, 0.f);
                db.x = fmaxf(db.x, 0.f); db.y = fmaxf(db.y, 0.f);
                Sp[j] = pk_add(Sp[j], pk_add(da, db));
            }
        }
        // ---- boundary post-pass: 128 g x 4 tasks, one thread each ----
        {
            int g = tid & 127, task = tid >> 7;
            float vw0 = wt[g * 3 + 0], vw1 = wt[g * 3 + 1], vw2 = wt[g * 3 + 2], vb = bt[g];
            float s = 0.f, first = 0.f, last = 0.f;
            int p0 = (task == 1) ? 63 * 64 : ((task == 3) ? 63 : 0);
            int stp = (task >= 2) ? 64 : 1;
            #pragma unroll 4
            for (int i = 0; i < 64; ++i) {
                int p = p0 + i * stp;
                float u = fmaxf(0.f, fmaf(vw0, lds[p], fmaf(vw1, lds[4096 + p], fmaf(vw2, lds[8192 + p], vb))));
                s += u;
                if (i == 0) first = u;
                if (i == 63) last = u;
            }
            Fsh[g * 9 + 1 + task] = s;          // R0,R63,C0,C63
            if (task == 0) { Fsh[g * 9 + 5] = first; Fsh[g * 9 + 6] = last; }   // u00, u0_63
            if (task == 1) { Fsh[g * 9 + 7] = first; Fsh[g * 9 + 8] = last; }   // u63_0, u63_63
        }
        __syncthreads();  // everyone done reading t planes
        // S-reduce across the 16 q-chunks: padded stride 17 -> conflict-free
        #pragma unroll
        for (int j = 0; j < 4; ++j) lds[(gl + 32 * j) * 17 + q] = Sp[j].x + Sp[j].y;
    }
    __syncthreads();
    if (tid < 128) {
        float s = 0.f;
        #pragma unroll
        for (int qq = 0; qq < 16; ++qq) s += lds[tid * 17 + qq];
        Fsh[tid * 9 + 0] = s;
    }
    __syncthreads();
    // contract: m[b,g] = (1/4096) * sum_j w2e[j][g] * Fsh[j], split over 4 j-chunks
    {
        int chunk = tid >> 7, g = tid & 127;
        float acc = 0.f;
        #pragma unroll 4
        for (int t = 0; t < 72; ++t) {
            int jb = chunk * 72 + t;
            float4 wv = *(const float4*)&w2e[(size_t)jb * 512 + g * 4];
            float4 fv = *(const float4*)&Fsh[jb * 4];
            acc = fmaf(wv.x, fv.x, fmaf(wv.y, fv.y, fmaf(wv.z, fv.z, fmaf(wv.w, fv.w, acc))));
        }
        __syncthreads();
        lds[chunk * 128 + g] = acc;
    }
    __syncthreads();
    if (tid < 128)
        m[b * 128 + tid] = (lds[tid] + lds[128 + tid] + lds[256 + tid] + lds[384 + tid]) * (1.f / 4096.f);
}

// ---------- kE: bn3 (redundant per-block batch stats) + all heads ----------
__global__ __launch_bounds__(256) void kE(
    const float* __restrict__ m, const float* __restrict__ g3, const float* __restrict__ b3,
    const float* __restrict__ agent, const float* __restrict__ action,
    const float* __restrict__ fc1w, const float* __restrict__ fc1b,
    const float* __restrict__ lnmig, const float* __restrict__ lnmib,
    const float* __restrict__ miw1, const float* __restrict__ miw2,
    const float* __restrict__ embc, const float* __restrict__ embe,
    const float* __restrict__ embnc, const float* __restrict__ embns,
    const float* __restrict__ embp,
    const float* __restrict__ lncag, const float* __restrict__ lncab,
    const float* __restrict__ caw1, const float* __restrict__ cab1,
    const float* __restrict__ caw2, const float* __restrict__ cab2,
    const float* __restrict__ lncg, const float* __restrict__ lncb,
    const float* __restrict__ cw,
    const float* __restrict__ lndg, const float* __restrict__ lndb,
    const float* __restrict__ dw1, const float* __restrict__ dw2,
    float* __restrict__ out) {
    __shared__ float red[4][128];
    __shared__ float xsh[128];
    __shared__ float lnv[28], lnca[24], lnsc[56], h1[100], h2[100], h3[50], cat[60];
    int b = blockIdx.x, tid = threadIdx.x;
    // bn3 batch stats (each block redundantly; m is 128KB, L2-hot)
    {
        int g = tid & 127, half = tid >> 7;
        float s = 0.f, s2 = 0.f;
        for (int i = 0; i < 128; ++i) {
            float v = m[(half * 128 + i) * 128 + g];
            s += v; s2 = fmaf(v, v, s2);
        }
        red[half * 2 + 0][g] = s;
        red[half * 2 + 1][g] = s2;
    }
    __syncthreads();
    if (tid < 128) {
        float s = red[0][tid] + red[2][tid], s2 = red[1][tid] + red[3][tid];
        float mean = s / 256.f, var = s2 / 256.f - mean * mean;
        float a = g3[tid] * rsqrtf(var + EPSF);
        float bb = b3[tid] - mean * a;
        xsh[tid] = fmaxf(0.f, fmaf(a, m[b * 128 + tid], bb));
    }
    // phase B: three LayerNorms, one per wave
    int l = tid & 63, w = tid >> 6;
    if (w == 0) {  // agent LN(28)
        float av = (l < 28) ? agent[b * 28 + l] : 0.f;
        float s = wave_sum(av), s2 = wave_sum(av * av);
        s = __shfl(s, 0); s2 = __shfl(s2, 0);
        float mean = s / 28.f, var = s2 / 28.f - mean * mean;
        float rs = rsqrtf(var + EPSF);
        if (l < 28) lnv[l] = (av - mean) * rs * lnmig[l] + lnmib[l];
    } else if (w == 1) {  // actions build + LN(24)
        const float* ab = action + b * 15;
        float actv = 0.f;
        if (l < 24) {
            if (l < 4)       actv = ab[l];
            else if (l < 7)  { int ix = (int)ab[4];  actv = embc[ix * 3 + (l - 4)]; }
            else if (l < 10) { int ix = (int)ab[5];  actv = embe[ix * 3 + (l - 7)]; }
            else if (l < 13) actv = ab[l - 4];
            else if (l < 16) { int ix = (int)ab[9];  actv = embnc[ix * 3 + (l - 13)]; }
            else if (l < 18) { int ix = (int)ab[10]; actv = embns[ix * 2 + (l - 16)]; }
            else if (l < 21) { int ix = (int)ab[11]; actv = embp[ix * 3 + (l - 18)]; }
            else             actv = ab[l - 9];
        }
        float s = wave_sum(actv), s2 = wave_sum(actv * actv);
        s = __shfl(s, 0); s2 = __shfl(s2, 0);
        float mean = s / 24.f, var = s2 / 24.f - mean * mean;
        float rs = rsqrtf(var + EPSF);
        if (l < 24) lnca[l] = (actv - mean) * rs * lncag[l] + lncab[l];
    } else if (w == 2) {  // dist LN(56): sc = [zeros(28), agent]
        float g1v = (l < 56) ? agent[b * 28 + (l < 28 ? l : l - 28)] : 0.f;
        float av = (l < 28) ? g1v : 0.f;
        float s = wave_sum(av), s2 = wave_sum(av * av);
        s = __shfl(s, 0); s2 = __shfl(s2, 0);
        float mean = s / 56.f, var = s2 / 56.f - mean * mean;
        float rs = rsqrtf(var + EPSF);
        if (l < 56) {
            float vv = (l < 28) ? 0.f : g1v;
            lnsc[l] = (vv - mean) * rs * lndg[l] + lndb[l];
        }
    }
    __syncthreads();
    // phase C: first-layer neurons, thread-parallel
    if (tid < 100) {
        float a = 0.f;
        for (int i = 0; i < 28; ++i) a = fmaf(miw1[tid * 28 + i], lnv[i], a);
        h1[tid] = fmaxf(0.f, a);
    } else if (tid < 200) {
        int j = tid - 100;
        float a = cab1[j];
        for (int i = 0; i < 24; ++i) a = fmaf(caw1[j * 24 + i], lnca[i], a);
        h2[j] = fmaxf(0.f, a);
    } else if (tid < 250) {
        int j = tid - 200;
        float a = 0.f;
        for (int i = 0; i < 56; ++i) a = fmaf(dw1[j * 56 + i], lnsc[i], a);
        h3[j] = tanhf(a);
    }
    __syncthreads();
    // phase D: second layers + dist output
    if (tid < 20) {
        float a = 0.f;
        for (int i = 0; i < 100; ++i) a = fmaf(miw2[tid * 100 + i], h1[i], a);
        cat[20 + tid] = fmaxf(0.f, a);
    } else if (tid >= 64 && tid < 84) {
        int j = tid - 64;
        float a = cab2[j];
        for (int i = 0; i < 100; ++i) a = fmaf(caw2[j * 100 + i], h2[i], a);
        cat[40 + j] = fmaxf(0.f, a);
    } else if (tid >= 128 && tid < 148) {
        int j = tid - 128;
        float a = fc1b[j];
        for (int i = 0; i < 128; ++i) a = fmaf(fc1w[j * 128 + i], xsh[i], a);
        cat[j] = fmaxf(0.f, a);
    } else if (tid >= 192) {
        int l3 = tid - 192;
        float dt = (l3 < 50) ? dw2[l3] * h3[l3] : 0.f;
        dt = wave_sum(dt);
        if (l3 == 0) out[256 + b] = tanhf(dt);
    }
    __syncthreads();
    // phase E: combined head LN(60) -> dot -> tanh (wave 0)
    if (w == 0) {
        float cv = (l < 60) ? cat[l] : 0.f;
        float ss = wave_sum(cv), ss2 = wave_sum(cv * cv);
        ss = __shfl(ss, 0); ss2 = __shfl(ss2, 0);
        float mean60 = ss / 60.f, var60 = ss2 / 60.f - mean60 * mean60;
        float rs60 = rsqrtf(var60 + EPSF);
        float term = (l < 60) ? cw[l] * ((cv - mean60) * rs60 * lncg[l] + lncb[l]) : 0.f;
        term = wave_sum(term);
        if (l == 0) out[b] = tanhf(term);
    }
}

extern "C" void kernel_launch(void* const* d_in, const int* in_sizes, int n_in,
                              void* d_out, int out_size, void* d_ws, size_t ws_size,
                              hipStream_t stream) {
    (void)in_sizes; (void)n_in; (void)out_size; (void)ws_size;
    const float* agent  = (const float*)d_in[0];
    const float* world  = (const float*)d_in[1];
    const float* action = (const float*)d_in[2];
    const float* bn1_g  = (const float*)d_in[3];
    const float* bn1_b  = (const float*)d_in[4];
    const float* conv1w = (const float*)d_in[5];
    const float* bn2_g  = (const float*)d_in[6];
    const float* bn2_b  = (const float*)d_in[7];
    const float* conv2w = (const float*)d_in[8];
    const float* bn3_g  = (const float*)d_in[9];
    const float* bn3_b  = (const float*)d_in[10];
    const float* fc1w   = (const float*)d_in[11];
    const float* fc1b   = (const float*)d_in[12];
    const float* lnmig  = (const float*)d_in[13];
    const float* lnmib  = (const float*)d_in[14];
    const float* miw1   = (const float*)d_in[15];
    const float* miw2   = (const float*)d_in[16];
    const float* embc   = (const float*)d_in[17];
    const float* embe   = (const float*)d_in[18];
    const float* embnc  = (const float*)d_in[19];
    const float* embns  = (const float*)d_in[20];
    const float* embp   = (const float*)d_in[21];
    const float* lncag  = (const float*)d_in[22];
    const float* lncab  = (const float*)d_in[23];
    const float* caw1   = (const float*)d_in[24];
    const float* cab1   = (const float*)d_in[25];
    const float* caw2   = (const float*)d_in[26];
    const float* cab2   = (const float*)d_in[27];
    const float* lncg   = (const float*)d_in[28];
    const float* lncb   = (const float*)d_in[29];
    const float* cw     = (const float*)d_in[30];
    const float* lndg   = (const float*)d_in[31];
    const float* lndb   = (const float*)d_in[32];
    const float* dw1    = (const float*)d_in[33];
    const float* dw2    = (const float*)d_in[34];
    float* out = (float*)d_out;
    float* ws = (float*)d_ws;

    hipLaunchKernelGGL(kA, dim3(256), dim3(256), 0, stream,
                       world, conv2w, ws + OFF_RED1, ws + OFF_W2E);
    hipLaunchKernelGGL(kB, dim3(256), dim3(256), 0, stream,
                       world, ws + OFF_RED1, bn1_g, bn1_b, ws + OFF_RED2, ws + OFF_A1B1);
    hipLaunchKernelGGL(kC, dim3(256), dim3(512), 0, stream,
                       world, ws + OFF_RED2, conv1w, bn2_g, bn2_b, ws + OFF_A1B1,
                       ws + OFF_W2E, ws + OFF_M);
    hipLaunchKernelGGL(kE, dim3(256), dim3(256), 0, stream,
                       ws + OFF_M, bn3_g, bn3_b, agent, action, fc1w, fc1b,
                       lnmig, lnmib, miw1, miw2,
                       embc, embe, embnc, embns, embp,
                       lncag, lncab, caw1, cab1, caw2, cab2,
                       lncg, lncb, cw, lndg, lndb, dw1, dw2, out);
}